// Round 1
// baseline (59803.558 us; speedup 1.0000x reference)
//
#include <hip/hip_runtime.h>
#include <cstdint>
#include <cstddef>

#define B_ 16
#define S_ 512
#define H_ 768
#define L_ 12
#define NH_ 12
#define DH_ 64
#define FF_ 3072
#define NL_ 9

// ---------------- block reduction helpers (blockDim == 256) ----------------
__device__ __forceinline__ float block_sum256(float v, float* red) {
#pragma unroll
  for (int off = 32; off; off >>= 1) v += __shfl_down(v, off);
  __syncthreads();
  if ((threadIdx.x & 63) == 0) red[threadIdx.x >> 6] = v;
  __syncthreads();
  return red[0] + red[1] + red[2] + red[3];
}

__device__ __forceinline__ float block_max256(float v, float* red) {
#pragma unroll
  for (int off = 32; off; off >>= 1) v = fmaxf(v, __shfl_down(v, off));
  __syncthreads();
  if ((threadIdx.x & 63) == 0) red[threadIdx.x >> 6] = v;
  __syncthreads();
  return fmaxf(fmaxf(red[0], red[1]), fmaxf(red[2], red[3]));
}

__device__ __forceinline__ float gelu_f(float x) {
  return 0.5f * x * (1.0f + erff(x * 0.70710678118654752f));
}

// ---------------- embeddings + LayerNorm ----------------
__global__ __launch_bounds__(256) void embed_ln_kernel(
    const int* __restrict__ wid, const int* __restrict__ tpid,
    const float* __restrict__ we, const float* __restrict__ pe,
    const float* __restrict__ te, const float* __restrict__ g,
    const float* __restrict__ bb, float* __restrict__ h) {
  __shared__ float red[4];
  int tok = blockIdx.x;
  int s = tok & (S_ - 1);
  int w = wid[tok], tp = tpid[tok];
  int t = threadIdx.x;
  float x[3];
#pragma unroll
  for (int i = 0; i < 3; ++i) {
    int j = t + i * 256;
    x[i] = we[(size_t)w * H_ + j] + pe[(size_t)s * H_ + j] + te[(size_t)tp * H_ + j];
  }
  float m = block_sum256(x[0] + x[1] + x[2], red) * (1.0f / H_);
  float d0 = x[0] - m, d1 = x[1] - m, d2 = x[2] - m;
  float var = block_sum256(d0 * d0 + d1 * d1 + d2 * d2, red) * (1.0f / H_);
  float rs = rsqrtf(var + 1e-12f);
#pragma unroll
  for (int i = 0; i < 3; ++i) {
    int j = t + i * 256;
    h[(size_t)tok * H_ + j] = (x[i] - m) * rs * g[j] + bb[j];
  }
}

// ---------------- residual add + LayerNorm (in place on h) ----------------
__global__ __launch_bounds__(256) void add_ln_kernel(
    float* __restrict__ h, const float* __restrict__ delta,
    const float* __restrict__ g, const float* __restrict__ bb) {
  __shared__ float red[4];
  int tok = blockIdx.x;
  int t = threadIdx.x;
  float x[3];
#pragma unroll
  for (int i = 0; i < 3; ++i) {
    int j = t + i * 256;
    x[i] = h[(size_t)tok * H_ + j] + delta[(size_t)tok * H_ + j];
  }
  float m = block_sum256(x[0] + x[1] + x[2], red) * (1.0f / H_);
  float d0 = x[0] - m, d1 = x[1] - m, d2 = x[2] - m;
  float var = block_sum256(d0 * d0 + d1 * d1 + d2 * d2, red) * (1.0f / H_);
  float rs = rsqrtf(var + 1e-12f);
#pragma unroll
  for (int i = 0; i < 3; ++i) {
    int j = t + i * 256;
    h[(size_t)tok * H_ + j] = (x[i] - m) * rs * g[j] + bb[j];
  }
}

// ---------------- generic fp32 GEMM: C = A[M,K] @ B[K,N] + bias, opt GELU ----
// 64x64 tile, BK=16, 256 threads, 4x4 per thread.
template <int ACT>
__global__ __launch_bounds__(256) void gemm_kernel(
    const float* __restrict__ A, const float* __restrict__ Bm,
    const float* __restrict__ bias, float* __restrict__ C,
    int M, int N, int K) {
  __shared__ float As[16][64];
  __shared__ float Bs[16][64];
  int tid = threadIdx.x;
  int tx = tid & 15, ty = tid >> 4;
  int row0 = blockIdx.y * 64, col0 = blockIdx.x * 64;
  int ar = tid >> 2, ac = (tid & 3) * 4;    // A tile: 64 rows x 16 cols
  int br = tid >> 4, bc = (tid & 15) * 4;   // B tile: 16 rows x 64 cols
  float acc[4][4] = {};
  for (int kk = 0; kk < K; kk += 16) {
    float4 a4 = *(const float4*)&A[(size_t)(row0 + ar) * K + kk + ac];
    As[ac + 0][ar] = a4.x;
    As[ac + 1][ar] = a4.y;
    As[ac + 2][ar] = a4.z;
    As[ac + 3][ar] = a4.w;
    float4 b4 = *(const float4*)&Bm[(size_t)(kk + br) * N + col0 + bc];
    *(float4*)&Bs[br][bc] = b4;
    __syncthreads();
#pragma unroll
    for (int kj = 0; kj < 16; ++kj) {
      float4 av = *(const float4*)&As[kj][ty * 4];
      float4 bv = *(const float4*)&Bs[kj][tx * 4];
      float aa[4] = {av.x, av.y, av.z, av.w};
      float bb2[4] = {bv.x, bv.y, bv.z, bv.w};
#pragma unroll
      for (int i = 0; i < 4; ++i)
#pragma unroll
        for (int j = 0; j < 4; ++j) acc[i][j] = fmaf(aa[i], bb2[j], acc[i][j]);
    }
    __syncthreads();
  }
  float4 bs4 = *(const float4*)&bias[col0 + tx * 4];
  float bsv[4] = {bs4.x, bs4.y, bs4.z, bs4.w};
#pragma unroll
  for (int i = 0; i < 4; ++i) {
    float o[4];
#pragma unroll
    for (int j = 0; j < 4; ++j) {
      float val = acc[i][j] + bsv[j];
      if (ACT == 1) val = gelu_f(val);
      o[j] = val;
    }
    *(float4*)&C[(size_t)(row0 + ty * 4 + i) * N + col0 + tx * 4] = *(float4*)o;
  }
}

// ---------------- attention: one block per (q-row, head, batch) ----------------
__global__ __launch_bounds__(256) void attn_kernel(
    const float* __restrict__ q, const float* __restrict__ k,
    const float* __restrict__ v, const int* __restrict__ mask,
    float* __restrict__ ctx) {
  __shared__ float sc[S_];
  __shared__ float qv[DH_];
  __shared__ float red[4];
  int qi = blockIdx.x, hd = blockIdx.y, b = blockIdx.z;
  int t = threadIdx.x;
  const float scale = 0.125f;  // 1/sqrt(64)
  if (t < DH_) qv[t] = q[((size_t)(b * S_ + qi) * H_) + hd * DH_ + t] * scale;
  __syncthreads();
  float lmax = -1e30f;
  float mysc[2];
#pragma unroll
  for (int r = 0; r < 2; ++r) {
    int ki = t + r * 256;
    const float4* kp = (const float4*)&k[((size_t)(b * S_ + ki) * H_) + hd * DH_];
    const float4* qp = (const float4*)qv;
    float dot = 0.f;
#pragma unroll
    for (int dd = 0; dd < DH_ / 4; ++dd) {
      float4 k4 = kp[dd];
      float4 q4 = qp[dd];
      dot += q4.x * k4.x + q4.y * k4.y + q4.z * k4.z + q4.w * k4.w;
    }
    dot += (1.0f - (float)mask[b * S_ + ki]) * -1e9f;
    mysc[r] = dot;
    lmax = fmaxf(lmax, dot);
  }
  float gmax = block_max256(lmax, red);
  float lsum = 0.f;
#pragma unroll
  for (int r = 0; r < 2; ++r) {
    float e = expf(mysc[r] - gmax);
    sc[t + r * 256] = e;
    lsum += e;
  }
  float gsum = block_sum256(lsum, red);  // internal syncs make sc[] visible
  float inv = 1.0f / gsum;
  int d = t & 63, part = t >> 6;
  float acc = 0.f;
  int k0 = part * 128;
  for (int ki = k0; ki < k0 + 128; ++ki) {
    acc += sc[ki] * v[((size_t)(b * S_ + ki) * H_) + hd * DH_ + d];
  }
  __syncthreads();   // all sc reads done
  sc[t] = acc;
  __syncthreads();
  if (t < 64) {
    float r2 = sc[t] + sc[t + 64] + sc[t + 128] + sc[t + 192];
    ctx[((size_t)(b * S_ + qi) * H_) + hd * DH_ + t] = r2 * inv;
  }
}

// ---------------- valid-token compaction ----------------
__global__ void compact_idx_kernel(const int* __restrict__ valid, int* __restrict__ dest) {
  int b = threadIdx.x;
  if (b >= B_) return;
  int cnt = 0;
  for (int s = 0; s < S_; ++s) {
    int vv = valid[b * S_ + s];
    dest[b * S_ + s] = vv ? cnt : -1;
    cnt += vv;
  }
}

__global__ __launch_bounds__(256) void scatter_kernel(
    const float* __restrict__ h, const int* __restrict__ dest,
    float* __restrict__ compact) {
  int tok = blockIdx.x;
  int d = dest[tok];
  if (d < 0) return;
  int b = tok >> 9;  // S_=512
  size_t src = (size_t)tok * H_;
  size_t dst = ((size_t)(b * S_ + d)) * H_;
  for (int j = threadIdx.x; j < H_; j += 256) compact[dst + j] = h[src + j];
}

// ---------------- classifier + softmax: one wave per token ----------------
__global__ __launch_bounds__(256) void cls_kernel(
    const float* __restrict__ x, const float* __restrict__ W,
    const float* __restrict__ bias2, float* __restrict__ out) {
  int lane = threadIdx.x & 63, wv = threadIdx.x >> 6;
  int tok = blockIdx.x * 4 + wv;
  float acc[NL_] = {};
  for (int hh = lane; hh < H_; hh += 64) {
    float xv = x[(size_t)tok * H_ + hh];
#pragma unroll
    for (int n = 0; n < NL_; ++n) acc[n] = fmaf(xv, W[hh * NL_ + n], acc[n]);
  }
#pragma unroll
  for (int n = 0; n < NL_; ++n) {
#pragma unroll
    for (int off = 32; off; off >>= 1) acc[n] += __shfl_down(acc[n], off);
  }
  if (lane == 0) {
    float vls[NL_], mx = -1e30f;
#pragma unroll
    for (int n = 0; n < NL_; ++n) {
      vls[n] = acc[n] + bias2[n];
      mx = fmaxf(mx, vls[n]);
    }
    float s = 0.f;
#pragma unroll
    for (int n = 0; n < NL_; ++n) {
      vls[n] = expf(vls[n] - mx);
      s += vls[n];
    }
    float inv = 1.0f / s;
#pragma unroll
    for (int n = 0; n < NL_; ++n) out[(size_t)tok * NL_ + n] = vls[n] * inv;
  }
}

extern "C" void kernel_launch(void* const* d_in, const int* in_sizes, int n_in,
                              void* d_out, int out_size, void* d_ws, size_t ws_size,
                              hipStream_t stream) {
  const int* wid = (const int*)d_in[0];
  const int* mask = (const int*)d_in[1];
  const int* tpid = (const int*)d_in[2];
  const int* valid = (const int*)d_in[3];
  const float* we = (const float*)d_in[4];
  const float* pe = (const float*)d_in[5];
  const float* te = (const float*)d_in[6];
  const float* eg = (const float*)d_in[7];
  const float* eb = (const float*)d_in[8];
  const float* Wq = (const float*)d_in[9];
  const float* bq = (const float*)d_in[10];
  const float* Wk = (const float*)d_in[11];
  const float* bk = (const float*)d_in[12];
  const float* Wv = (const float*)d_in[13];
  const float* bv = (const float*)d_in[14];
  const float* Wo = (const float*)d_in[15];
  const float* bo = (const float*)d_in[16];
  const float* g1 = (const float*)d_in[17];
  const float* gb1 = (const float*)d_in[18];
  const float* W1 = (const float*)d_in[19];
  const float* bf1 = (const float*)d_in[20];
  const float* W2 = (const float*)d_in[21];
  const float* bf2 = (const float*)d_in[22];
  const float* g2 = (const float*)d_in[23];
  const float* gb2 = (const float*)d_in[24];
  const float* cW = (const float*)d_in[25];
  const float* cb = (const float*)d_in[26];
  float* out = (float*)d_out;

  const size_t TOK = (size_t)B_ * S_;  // 8192
  float* ws = (float*)d_ws;
  float* h = ws;                    // [8192,768]
  float* t1 = h + TOK * H_;         // [8192,768]  (ctx / ff2-out)
  float* big = t1 + TOK * H_;       // [8192,3072] (qkv during attn, ff hidden)
  float* qb = big;
  float* kb = big + TOK * H_;
  float* vb = big + 2 * TOK * H_;
  int* dest = (int*)(big + TOK * FF_);  // [8192] ints
  float* compact = big;                 // reused after layers

  dim3 blk(256);
  embed_ln_kernel<<<dim3((unsigned)TOK), blk, 0, stream>>>(wid, tpid, we, pe, te, eg, eb, h);

  dim3 gH(H_ / 64, TOK / 64);    // N=768 GEMMs
  dim3 gF(FF_ / 64, TOK / 64);   // N=3072 GEMM
  for (int l = 0; l < L_; ++l) {
    const float* wq = Wq + (size_t)l * H_ * H_;
    const float* wk = Wk + (size_t)l * H_ * H_;
    const float* wv = Wv + (size_t)l * H_ * H_;
    const float* wo = Wo + (size_t)l * H_ * H_;
    const float* w1 = W1 + (size_t)l * H_ * FF_;
    const float* w2 = W2 + (size_t)l * FF_ * H_;

    gemm_kernel<0><<<gH, blk, 0, stream>>>(h, wq, bq + l * H_, qb, (int)TOK, H_, H_);
    gemm_kernel<0><<<gH, blk, 0, stream>>>(h, wk, bk + l * H_, kb, (int)TOK, H_, H_);
    gemm_kernel<0><<<gH, blk, 0, stream>>>(h, wv, bv + l * H_, vb, (int)TOK, H_, H_);
    attn_kernel<<<dim3(S_, NH_, B_), blk, 0, stream>>>(qb, kb, vb, mask, t1);
    gemm_kernel<0><<<gH, blk, 0, stream>>>(t1, wo, bo + l * H_, qb, (int)TOK, H_, H_);
    add_ln_kernel<<<dim3((unsigned)TOK), blk, 0, stream>>>(h, qb, g1 + l * H_, gb1 + l * H_);
    gemm_kernel<1><<<gF, blk, 0, stream>>>(h, w1, bf1 + l * FF_, big, (int)TOK, FF_, H_);
    gemm_kernel<0><<<gH, blk, 0, stream>>>(big, w2, bf2 + l * H_, t1, (int)TOK, H_, FF_);
    add_ln_kernel<<<dim3((unsigned)TOK), blk, 0, stream>>>(h, t1, g2 + l * H_, gb2 + l * H_);
  }

  compact_idx_kernel<<<1, 64, 0, stream>>>(valid, dest);
  hipMemsetAsync(compact, 0, TOK * H_ * sizeof(float), stream);
  scatter_kernel<<<dim3((unsigned)TOK), blk, 0, stream>>>(h, dest, compact);
  cls_kernel<<<dim3((unsigned)(TOK / 4)), blk, 0, stream>>>(compact, cW, cb, out);
}

// Round 2
// 4042.060 us; speedup vs baseline: 14.7953x; 14.7953x over previous
//
#include <hip/hip_runtime.h>
#include <cstdint>
#include <cstddef>

#define B_ 16
#define S_ 512
#define H_ 768
#define L_ 12
#define NH_ 12
#define DH_ 64
#define FF_ 3072
#define NL_ 9

typedef _Float16 f16x8 __attribute__((ext_vector_type(8)));
typedef float f32x4 __attribute__((ext_vector_type(4)));

// ---------------- block reduction helpers (blockDim == 256) ----------------
__device__ __forceinline__ float block_sum256(float v, float* red) {
#pragma unroll
  for (int off = 32; off; off >>= 1) v += __shfl_down(v, off);
  __syncthreads();
  if ((threadIdx.x & 63) == 0) red[threadIdx.x >> 6] = v;
  __syncthreads();
  return red[0] + red[1] + red[2] + red[3];
}

__device__ __forceinline__ float gelu_f(float x) {
  return 0.5f * x * (1.0f + erff(x * 0.70710678118654752f));
}

// ---------------- embeddings + LayerNorm (writes f32 h and f16 hb) ----------
__global__ __launch_bounds__(256) void embed_ln_kernel(
    const int* __restrict__ wid, const int* __restrict__ tpid,
    const float* __restrict__ we, const float* __restrict__ pe,
    const float* __restrict__ te, const float* __restrict__ g,
    const float* __restrict__ bb, float* __restrict__ h,
    _Float16* __restrict__ hb) {
  __shared__ float red[4];
  int tok = blockIdx.x;
  int s = tok & (S_ - 1);
  int w = wid[tok], tp = tpid[tok];
  int t = threadIdx.x;
  float x[3];
#pragma unroll
  for (int i = 0; i < 3; ++i) {
    int j = t + i * 256;
    x[i] = we[(size_t)w * H_ + j] + pe[(size_t)s * H_ + j] + te[(size_t)tp * H_ + j];
  }
  float m = block_sum256(x[0] + x[1] + x[2], red) * (1.0f / H_);
  float d0 = x[0] - m, d1 = x[1] - m, d2 = x[2] - m;
  float var = block_sum256(d0 * d0 + d1 * d1 + d2 * d2, red) * (1.0f / H_);
  float rs = rsqrtf(var + 1e-12f);
#pragma unroll
  for (int i = 0; i < 3; ++i) {
    int j = t + i * 256;
    float v = (x[i] - m) * rs * g[j] + bb[j];
    h[(size_t)tok * H_ + j] = v;
    hb[(size_t)tok * H_ + j] = (_Float16)v;
  }
}

// ---------------- residual add + LayerNorm (updates h, writes hb) -----------
__global__ __launch_bounds__(256) void add_ln_kernel(
    float* __restrict__ h, const float* __restrict__ delta,
    const float* __restrict__ g, const float* __restrict__ bb,
    _Float16* __restrict__ hb) {
  __shared__ float red[4];
  int tok = blockIdx.x;
  int t = threadIdx.x;
  float x[3];
#pragma unroll
  for (int i = 0; i < 3; ++i) {
    int j = t + i * 256;
    x[i] = h[(size_t)tok * H_ + j] + delta[(size_t)tok * H_ + j];
  }
  float m = block_sum256(x[0] + x[1] + x[2], red) * (1.0f / H_);
  float d0 = x[0] - m, d1 = x[1] - m, d2 = x[2] - m;
  float var = block_sum256(d0 * d0 + d1 * d1 + d2 * d2, red) * (1.0f / H_);
  float rs = rsqrtf(var + 1e-12f);
#pragma unroll
  for (int i = 0; i < 3; ++i) {
    int j = t + i * 256;
    float v = (x[i] - m) * rs * g[j] + bb[j];
    h[(size_t)tok * H_ + j] = v;
    hb[(size_t)tok * H_ + j] = (_Float16)v;
  }
}

// ---------------- per-layer weight convert + transpose: f32 [K][N] -> f16 [N][K]
// 1728 blocks: 0..575 = Wq/Wk/Wv/Wo (768x768), 576..1151 = W1 (768x3072),
// 1152..1727 = W2 (3072x768). 64x64 tiles.
__global__ __launch_bounds__(256) void convert_weights_kernel(
    const float* __restrict__ Wq, const float* __restrict__ Wk,
    const float* __restrict__ Wv, const float* __restrict__ Wo,
    const float* __restrict__ W1, const float* __restrict__ W2,
    _Float16* __restrict__ qT, _Float16* __restrict__ kT,
    _Float16* __restrict__ vT, _Float16* __restrict__ oT,
    _Float16* __restrict__ w1T, _Float16* __restrict__ w2T) {
  __shared__ float T[64][65];
  int id = blockIdx.x;
  const float* src;
  _Float16* dst;
  int K, N, tk, tn;
  if (id < 576) {
    int mat = id / 144, t = id % 144;
    K = 768; N = 768; tk = t / 12; tn = t % 12;
    src = (mat == 0) ? Wq : (mat == 1) ? Wk : (mat == 2) ? Wv : Wo;
    dst = (mat == 0) ? qT : (mat == 1) ? kT : (mat == 2) ? vT : oT;
  } else if (id < 1152) {
    int t = id - 576; K = 768; N = 3072; tk = t / 48; tn = t % 48;
    src = W1; dst = w1T;
  } else {
    int t = id - 1152; K = 3072; N = 768; tk = t / 12; tn = t % 12;
    src = W2; dst = w2T;
  }
  int tid = threadIdx.x;
  int k0 = tk * 64, n0 = tn * 64;
  {
    int r = tid >> 4, c4 = (tid & 15) * 4;
#pragma unroll
    for (int i = 0; i < 4; ++i) {
      float4 v = *(const float4*)&src[(size_t)(k0 + r + i * 16) * N + n0 + c4];
      T[r + i * 16][c4 + 0] = v.x;
      T[r + i * 16][c4 + 1] = v.y;
      T[r + i * 16][c4 + 2] = v.z;
      T[r + i * 16][c4 + 3] = v.w;
    }
  }
  __syncthreads();
#pragma unroll
  for (int i = 0; i < 2; ++i) {
    int chunk = tid + i * 256;  // 512 chunks: n = chunk>>3, kc = (chunk&7)*8
    int n = chunk >> 3, kc = (chunk & 7) * 8;
    f16x8 o;
#pragma unroll
    for (int j = 0; j < 8; ++j) o[j] = (_Float16)T[kc + j][n];
    *(f16x8*)&dst[(size_t)(n0 + n) * K + k0 + kc] = o;
  }
}

// ---------------- f16 MFMA GEMM: C = A[M,K] @ Bt[N,K]^T + bias ---------------
// 128x128 tile, BK=32, 256 threads (2x2 waves, 64x64 per wave, 4x4 16x16 frags)
// OUT: 0 = f32, 1 = f16, 2 = f16 + exact GELU
template <int OUT>
__global__ __launch_bounds__(256) void gemm_f16(
    const _Float16* __restrict__ A, const _Float16* __restrict__ Bt,
    const float* __restrict__ bias, void* __restrict__ Cv,
    int M, int N, int K) {
  __shared__ _Float16 As[128 * 40];  // [row][32 k + 8 pad]
  __shared__ _Float16 Bs[128 * 40];
  int tid = threadIdx.x;
  int lane = tid & 63, w = tid >> 6;
  int wr = w >> 1, wc = w & 1;
  int row0 = blockIdx.y * 128, col0 = blockIdx.x * 128;
  int l15 = lane & 15, kb = lane >> 4;

  int sr = tid >> 2, sc = tid & 3;  // staging: row sr (+64 for 2nd inst), chunk sc
  const f16x8* ag0 = (const f16x8*)&A[(size_t)(row0 + sr) * K + sc * 8];
  const f16x8* ag1 = (const f16x8*)&A[(size_t)(row0 + 64 + sr) * K + sc * 8];
  const f16x8* bg0 = (const f16x8*)&Bt[(size_t)(col0 + sr) * K + sc * 8];
  const f16x8* bg1 = (const f16x8*)&Bt[(size_t)(col0 + 64 + sr) * K + sc * 8];
  f16x8* aw0 = (f16x8*)&As[sr * 40 + sc * 8];
  f16x8* aw1 = (f16x8*)&As[(64 + sr) * 40 + sc * 8];
  f16x8* bw0 = (f16x8*)&Bs[sr * 40 + sc * 8];
  f16x8* bw1 = (f16x8*)&Bs[(64 + sr) * 40 + sc * 8];

  f32x4 acc[4][4] = {};
  f16x8 ra0 = ag0[0], ra1 = ag1[0], rb0 = bg0[0], rb1 = bg1[0];
  int nk = K >> 5;
  for (int kt = 0; kt < nk; ++kt) {
    __syncthreads();
    *aw0 = ra0; *aw1 = ra1; *bw0 = rb0; *bw1 = rb1;
    __syncthreads();
    if (kt + 1 < nk) {
      int off = (kt + 1) * 4;  // in f16x8 units (32 elems)
      ra0 = ag0[off]; ra1 = ag1[off]; rb0 = bg0[off]; rb1 = bg1[off];
    }
    f16x8 af[4], bf[4];
#pragma unroll
    for (int m = 0; m < 4; ++m)
      af[m] = *(const f16x8*)&As[(wr * 64 + m * 16 + l15) * 40 + kb * 8];
#pragma unroll
    for (int n = 0; n < 4; ++n)
      bf[n] = *(const f16x8*)&Bs[(wc * 64 + n * 16 + l15) * 40 + kb * 8];
#pragma unroll
    for (int m = 0; m < 4; ++m)
#pragma unroll
      for (int n = 0; n < 4; ++n)
        acc[m][n] = __builtin_amdgcn_mfma_f32_16x16x32_f16(af[m], bf[n], acc[m][n], 0, 0, 0);
  }
#pragma unroll
  for (int n = 0; n < 4; ++n) {
    int col = col0 + wc * 64 + n * 16 + l15;
    float bv = bias[col];
#pragma unroll
    for (int m = 0; m < 4; ++m) {
      int rowb = row0 + wr * 64 + m * 16 + kb * 4;
#pragma unroll
      for (int r = 0; r < 4; ++r) {
        float v = acc[m][n][r] + bv;
        if (OUT == 2) v = gelu_f(v);
        if (OUT == 0)
          ((float*)Cv)[(size_t)(rowb + r) * N + col] = v;
        else
          ((_Float16*)Cv)[(size_t)(rowb + r) * N + col] = (_Float16)v;
      }
    }
  }
}

// ---------------- V transpose per head: vb [tok][768] -> vt [b*12+h][64][512]
__global__ __launch_bounds__(256) void vtrans_kernel(
    const _Float16* __restrict__ vb, _Float16* __restrict__ vt) {
  __shared__ _Float16 T[64][72];
  int s0 = blockIdx.x * 64;
  int bh = blockIdx.y;
  int b = bh / NH_, h = bh % NH_;
  int tid = threadIdx.x;
#pragma unroll
  for (int i = 0; i < 2; ++i) {
    int chunk = tid + i * 256;  // s = chunk>>3, dc = (chunk&7)*8
    int s = chunk >> 3, dc = (chunk & 7) * 8;
    *(f16x8*)&T[s][dc] = *(const f16x8*)&vb[(size_t)(b * S_ + s0 + s) * H_ + h * DH_ + dc];
  }
  __syncthreads();
#pragma unroll
  for (int i = 0; i < 2; ++i) {
    int chunk = tid + i * 256;  // d = chunk>>3, sc = (chunk&7)*8
    int d = chunk >> 3, sc = (chunk & 7) * 8;
    f16x8 o;
#pragma unroll
    for (int j = 0; j < 8; ++j) o[j] = T[sc + j][d];
    *(f16x8*)&vt[(size_t)(bh * DH_ + d) * S_ + s0 + sc] = o;
  }
}

// ---------------- fused flash attention, f16 MFMA ---------------------------
// grid (8 q-tiles, 12 heads, 16 batch), 256 threads = 4 waves x 16 q-rows.
__global__ __launch_bounds__(256) void flash_attn_kernel(
    const _Float16* __restrict__ q, const _Float16* __restrict__ k,
    const _Float16* __restrict__ vt, const int* __restrict__ mask,
    _Float16* __restrict__ ctx) {
  __shared__ _Float16 Ks[128 * 72];      // [key][64 d + pad]
  __shared__ _Float16 Vs[64 * 136];      // [d][128 keys + pad]
  __shared__ _Float16 Ps[4][16 * 136];   // per-wave P [16 q][128 k + pad]
  __shared__ float biasz[S_];
  int qt = blockIdx.x, h = blockIdx.y, b = blockIdx.z;
  int tid = threadIdx.x, lane = tid & 63, w = tid >> 6;
  int l15 = lane & 15, kb = lane >> 4;
  const float C = 0.125f * 1.44269504088896f;  // (1/sqrt(64)) * log2(e)

  for (int i = tid; i < S_; i += 256)
    biasz[i] = (1.0f - (float)mask[b * S_ + i]) * (-1e9f * C);

  int qrow = b * S_ + qt * 64 + w * 16 + l15;
  f16x8 qf[2];
  qf[0] = *(const f16x8*)&q[(size_t)qrow * H_ + h * DH_ + kb * 8];
  qf[1] = *(const f16x8*)&q[(size_t)qrow * H_ + h * DH_ + 32 + kb * 8];

  auto loadKV = [&](int kt, f16x8* rk, f16x8* rv) {
#pragma unroll
    for (int i = 0; i < 4; ++i) {
      int idx = tid + i * 256;
      int r = idx >> 3, c = idx & 7;          // K: 128 rows x 8 chunks
      rk[i] = *(const f16x8*)&k[(size_t)(b * S_ + kt * 128 + r) * H_ + h * DH_ + c * 8];
      int d = idx >> 4, c2 = idx & 15;        // V: 64 rows x 16 chunks
      rv[i] = *(const f16x8*)&vt[(size_t)((b * NH_ + h) * DH_ + d) * S_ + kt * 128 + c2 * 8];
    }
  };

  float m_run[4], l_run[4];
  f32x4 o[4] = {};
#pragma unroll
  for (int r = 0; r < 4; ++r) { m_run[r] = -1e30f; l_run[r] = 0.f; }

  f16x8 rk[4], rv[4];
  loadKV(0, rk, rv);
  for (int kt = 0; kt < 4; ++kt) {
    __syncthreads();
#pragma unroll
    for (int i = 0; i < 4; ++i) {
      int idx = tid + i * 256;
      int r = idx >> 3, c = idx & 7;
      *(f16x8*)&Ks[r * 72 + c * 8] = rk[i];
      int d = idx >> 4, c2 = idx & 15;
      *(f16x8*)&Vs[d * 136 + c2 * 8] = rv[i];
    }
    __syncthreads();
    if (kt < 3) loadKV(kt + 1, rk, rv);
    // QK^T: S-tile 16 q x 128 keys per wave
    f32x4 s[8];
#pragma unroll
    for (int nf = 0; nf < 8; ++nf) {
      f16x8 b0 = *(const f16x8*)&Ks[(nf * 16 + l15) * 72 + kb * 8];
      f16x8 b1 = *(const f16x8*)&Ks[(nf * 16 + l15) * 72 + 32 + kb * 8];
      f32x4 z = {};
      z = __builtin_amdgcn_mfma_f32_16x16x32_f16(qf[0], b0, z, 0, 0, 0);
      z = __builtin_amdgcn_mfma_f32_16x16x32_f16(qf[1], b1, z, 0, 0, 0);
      s[nf] = z;
    }
    float zb[8];
#pragma unroll
    for (int nf = 0; nf < 8; ++nf) zb[nf] = biasz[kt * 128 + nf * 16 + l15];
    float pw[8][4];
    float corr[4];
#pragma unroll
    for (int r = 0; r < 4; ++r) {
      float mx = -1e30f;
#pragma unroll
      for (int nf = 0; nf < 8; ++nf) mx = fmaxf(mx, s[nf][r] * C + zb[nf]);
#pragma unroll
      for (int d = 1; d < 16; d <<= 1) mx = fmaxf(mx, __shfl_xor(mx, d));
      float mnew = fmaxf(m_run[r], mx);
      float cr = exp2f(m_run[r] - mnew);
      m_run[r] = mnew;
      corr[r] = cr;
      float sum = 0.f;
#pragma unroll
      for (int nf = 0; nf < 8; ++nf) {
        float pv = exp2f(s[nf][r] * C + zb[nf] - mnew);
        pw[nf][r] = pv;
        sum += pv;
      }
#pragma unroll
      for (int d = 1; d < 16; d <<= 1) sum += __shfl_xor(sum, d);
      l_run[r] = l_run[r] * cr + sum;
    }
#pragma unroll
    for (int nf2 = 0; nf2 < 4; ++nf2)
#pragma unroll
      for (int r = 0; r < 4; ++r) o[nf2][r] *= corr[r];
    // write P (C-layout -> LDS row-major [q][key]) in wave-private tile
#pragma unroll
    for (int nf = 0; nf < 8; ++nf)
#pragma unroll
      for (int r = 0; r < 4; ++r)
        Ps[w][(kb * 4 + r) * 136 + nf * 16 + l15] = (_Float16)pw[nf][r];
    // PV: o[d-frag] += P[16q x 32k] * V[32k x 16d]
#pragma unroll
    for (int ks = 0; ks < 4; ++ks) {
      f16x8 pa = *(const f16x8*)&Ps[w][l15 * 136 + ks * 32 + kb * 8];
#pragma unroll
      for (int nf2 = 0; nf2 < 4; ++nf2) {
        f16x8 vb2 = *(const f16x8*)&Vs[(nf2 * 16 + l15) * 136 + ks * 32 + kb * 8];
        o[nf2] = __builtin_amdgcn_mfma_f32_16x16x32_f16(pa, vb2, o[nf2], 0, 0, 0);
      }
    }
  }
  float inv[4];
#pragma unroll
  for (int r = 0; r < 4; ++r) inv[r] = 1.0f / fmaxf(l_run[r], 1e-37f);
#pragma unroll
  for (int nf2 = 0; nf2 < 4; ++nf2)
#pragma unroll
    for (int r = 0; r < 4; ++r) {
      int row = b * S_ + qt * 64 + w * 16 + kb * 4 + r;
      ctx[(size_t)row * H_ + h * DH_ + nf2 * 16 + l15] = (_Float16)(o[nf2][r] * inv[r]);
    }
}

// ---------------- valid-token compaction ----------------
__global__ void compact_idx_kernel(const int* __restrict__ valid, int* __restrict__ dest) {
  int b = threadIdx.x;
  if (b >= B_) return;
  int cnt = 0;
  for (int s = 0; s < S_; ++s) {
    int vv = valid[b * S_ + s];
    dest[b * S_ + s] = vv ? cnt : -1;
    cnt += vv;
  }
}

__global__ __launch_bounds__(256) void scatter_kernel(
    const float* __restrict__ h, const int* __restrict__ dest,
    float* __restrict__ compact) {
  int tok = blockIdx.x;
  int d = dest[tok];
  if (d < 0) return;
  int b = tok >> 9;
  size_t src = (size_t)tok * H_;
  size_t dst = ((size_t)(b * S_ + d)) * H_;
  for (int j = threadIdx.x; j < H_; j += 256) compact[dst + j] = h[src + j];
}

// ---------------- classifier + softmax: one wave per token ----------------
__global__ __launch_bounds__(256) void cls_kernel(
    const float* __restrict__ x, const float* __restrict__ W,
    const float* __restrict__ bias2, float* __restrict__ out) {
  int lane = threadIdx.x & 63, wv = threadIdx.x >> 6;
  int tok = blockIdx.x * 4 + wv;
  float acc[NL_] = {};
  for (int hh = lane; hh < H_; hh += 64) {
    float xv = x[(size_t)tok * H_ + hh];
#pragma unroll
    for (int n = 0; n < NL_; ++n) acc[n] = fmaf(xv, W[hh * NL_ + n], acc[n]);
  }
#pragma unroll
  for (int n = 0; n < NL_; ++n) {
#pragma unroll
    for (int off = 32; off; off >>= 1) acc[n] += __shfl_down(acc[n], off);
  }
  if (lane == 0) {
    float vls[NL_], mx = -1e30f;
#pragma unroll
    for (int n = 0; n < NL_; ++n) {
      vls[n] = acc[n] + bias2[n];
      mx = fmaxf(mx, vls[n]);
    }
    float s = 0.f;
#pragma unroll
    for (int n = 0; n < NL_; ++n) {
      vls[n] = expf(vls[n] - mx);
      s += vls[n];
    }
    float inv = 1.0f / s;
#pragma unroll
    for (int n = 0; n < NL_; ++n) out[(size_t)tok * NL_ + n] = vls[n] * inv;
  }
}

extern "C" void kernel_launch(void* const* d_in, const int* in_sizes, int n_in,
                              void* d_out, int out_size, void* d_ws, size_t ws_size,
                              hipStream_t stream) {
  const int* wid = (const int*)d_in[0];
  const int* mask = (const int*)d_in[1];
  const int* tpid = (const int*)d_in[2];
  const int* valid = (const int*)d_in[3];
  const float* we = (const float*)d_in[4];
  const float* pe = (const float*)d_in[5];
  const float* te = (const float*)d_in[6];
  const float* eg = (const float*)d_in[7];
  const float* eb = (const float*)d_in[8];
  const float* Wq = (const float*)d_in[9];
  const float* bq = (const float*)d_in[10];
  const float* Wk = (const float*)d_in[11];
  const float* bk = (const float*)d_in[12];
  const float* Wv = (const float*)d_in[13];
  const float* bv = (const float*)d_in[14];
  const float* Wo = (const float*)d_in[15];
  const float* bo = (const float*)d_in[16];
  const float* g1 = (const float*)d_in[17];
  const float* gb1 = (const float*)d_in[18];
  const float* W1 = (const float*)d_in[19];
  const float* bf1 = (const float*)d_in[20];
  const float* W2 = (const float*)d_in[21];
  const float* bf2 = (const float*)d_in[22];
  const float* g2 = (const float*)d_in[23];
  const float* gb2 = (const float*)d_in[24];
  const float* cW = (const float*)d_in[25];
  const float* cb = (const float*)d_in[26];
  float* out = (float*)d_out;

  const size_t TOK = (size_t)B_ * S_;  // 8192
  char* ws = (char*)d_ws;
  float* h = (float*)ws;                              // 25,165,824 B
  _Float16* hb = (_Float16*)(ws + 25165824);          // 12,582,912 B
  float* t1 = (float*)(ws + 37748736);                // 25,165,824 B (also compact)
  char* un1 = ws + 62914560;                          // 50,331,648 B union
  _Float16* qb = (_Float16*)un1;
  _Float16* kb = (_Float16*)(un1 + 12582912);
  _Float16* vb = (_Float16*)(un1 + 25165824);
  _Float16* vt = (_Float16*)(un1 + 37748736);
  _Float16* ffh = (_Float16*)un1;                     // overlays qb/kb/vb/vt
  _Float16* ctx = (_Float16*)(ws + 113246208);        // 12,582,912 B
  char* wbuf = ws + 125829120;                        // 14,155,776 B
  _Float16* wqT = (_Float16*)wbuf;
  _Float16* wkT = (_Float16*)(wbuf + 1179648);
  _Float16* wvT = (_Float16*)(wbuf + 2359296);
  _Float16* woT = (_Float16*)(wbuf + 3538944);
  _Float16* w1T = (_Float16*)(wbuf + 4718592);
  _Float16* w2T = (_Float16*)(wbuf + 9437184);
  int* dest = (int*)(ws + 139984896);                 // 32,768 B

  dim3 blk(256);
  embed_ln_kernel<<<dim3((unsigned)TOK), blk, 0, stream>>>(wid, tpid, we, pe, te, eg, eb, h, hb);

  dim3 gH(H_ / 128, TOK / 128);   // (6, 64)
  dim3 gF(FF_ / 128, TOK / 128);  // (24, 64)
  for (int l = 0; l < L_; ++l) {
    convert_weights_kernel<<<dim3(1728), blk, 0, stream>>>(
        Wq + (size_t)l * H_ * H_, Wk + (size_t)l * H_ * H_,
        Wv + (size_t)l * H_ * H_, Wo + (size_t)l * H_ * H_,
        W1 + (size_t)l * H_ * FF_, W2 + (size_t)l * FF_ * H_,
        wqT, wkT, wvT, woT, w1T, w2T);
    gemm_f16<1><<<gH, blk, 0, stream>>>(hb, wqT, bq + l * H_, qb, (int)TOK, H_, H_);
    gemm_f16<1><<<gH, blk, 0, stream>>>(hb, wkT, bk + l * H_, kb, (int)TOK, H_, H_);
    gemm_f16<1><<<gH, blk, 0, stream>>>(hb, wvT, bv + l * H_, vb, (int)TOK, H_, H_);
    vtrans_kernel<<<dim3(S_ / 64, B_ * NH_), blk, 0, stream>>>(vb, vt);
    flash_attn_kernel<<<dim3(S_ / 64, NH_, B_), blk, 0, stream>>>(qb, kb, vt, mask, ctx);
    gemm_f16<0><<<gH, blk, 0, stream>>>(ctx, woT, bo + l * H_, t1, (int)TOK, H_, H_);
    add_ln_kernel<<<dim3((unsigned)TOK), blk, 0, stream>>>(h, t1, g1 + l * H_, gb1 + l * H_, hb);
    gemm_f16<2><<<gF, blk, 0, stream>>>(hb, w1T, bf1 + l * FF_, ffh, (int)TOK, FF_, H_);
    gemm_f16<0><<<gH, blk, 0, stream>>>(ffh, w2T, bf2 + l * H_, t1, (int)TOK, H_, FF_);
    add_ln_kernel<<<dim3((unsigned)TOK), blk, 0, stream>>>(h, t1, g2 + l * H_, gb2 + l * H_, hb);
  }

  compact_idx_kernel<<<1, 64, 0, stream>>>(valid, dest);
  hipMemsetAsync(t1, 0, TOK * H_ * sizeof(float), stream);
  scatter_kernel<<<dim3((unsigned)TOK), blk, 0, stream>>>(h, dest, t1);
  cls_kernel<<<dim3((unsigned)(TOK / 4)), blk, 0, stream>>>(t1, cW, cb, out);
}